// Round 4
// baseline (2370.906 us; speedup 1.0000x reference)
//
#include <hip/hip_runtime.h>

#define NBATCH 16
#define NPTS   1024
#define NDIM   1024
#define EPSI   1e-3f
#define QSCALE 127.5f
#define SPIN_TIMEOUT_TICKS (1ull << 28)   // s_memrealtime ticks; >>1000x any real wait

typedef __attribute__((ext_vector_type(8))) short short8;
typedef __attribute__((ext_vector_type(4))) float f32x4;

__device__ __forceinline__ unsigned short f2bf(float f) {
  union { float f; unsigned u; } v; v.f = f;
  unsigned r = v.u + 0x7fffu + ((v.u >> 16) & 1u);
  return (unsigned short)(r >> 16);
}

// device-coherent scalar access (per-access sc bits; NO cache-wide fences)
__device__ __forceinline__ float ld_agent(const float* p) {
  return __hip_atomic_load(p, __ATOMIC_RELAXED, __HIP_MEMORY_SCOPE_AGENT);
}
__device__ __forceinline__ void st_agent(float* p, float v) {
  __hip_atomic_store(p, v, __ATOMIC_RELAXED, __HIP_MEMORY_SCOPE_AGENT);
}
__device__ __forceinline__ unsigned long long ld_agent64(const unsigned long long* p) {
  return __hip_atomic_load(p, __ATOMIC_RELAXED, __HIP_MEMORY_SCOPE_AGENT);
}

// ---------------- normalize: fp32 [B,N,D] -> unit rows, bf16 ----------------
__global__ __launch_bounds__(256) void norm_kernel(const float* __restrict__ x,
                                                   const float* __restrict__ y,
                                                   unsigned short* __restrict__ xf,
                                                   unsigned short* __restrict__ yf) {
  int row = blockIdx.x;
  const float* src; unsigned short* dst;
  if (row < NBATCH * NPTS) { src = x; dst = xf; }
  else { row -= NBATCH * NPTS; src = y; dst = yf; }
  src += (size_t)row * NDIM; dst += (size_t)row * NDIM;
  const int t = threadIdx.x;
  float4 val = ((const float4*)src)[t];
  float ss = val.x*val.x + val.y*val.y + val.z*val.z + val.w*val.w;
  #pragma unroll
  for (int o = 32; o; o >>= 1) ss += __shfl_xor(ss, o, 64);
  __shared__ float wsum[4];
  if ((t & 63) == 0) wsum[t >> 6] = ss;
  __syncthreads();
  float tot = wsum[0] + wsum[1] + wsum[2] + wsum[3];
  float inv = 1.0f / fmaxf(sqrtf(tot), 1e-12f);
  ushort4 o4;
  o4.x = f2bf(val.x * inv); o4.y = f2bf(val.y * inv);
  o4.z = f2bf(val.z * inv); o4.w = f2bf(val.w * inv);
  ((ushort4*)dst)[t] = o4;
}

// ------- batched bf16 GEMM: writes BOTH Cq = q8(1 - A B^T) and its transpose -------
#define GLD_LDS16(g, l) __builtin_amdgcn_global_load_lds( \
    (const __attribute__((address_space(1))) unsigned int*)(g), \
    (__attribute__((address_space(3))) unsigned int*)(l), 16, 0, 0)

__device__ __forceinline__ unsigned char q8(float cv) {
  float t = cv * QSCALE + 0.5f;
  t = fminf(fmaxf(t, 0.f), 255.f);
  return (unsigned char)(int)t;
}

__global__ __launch_bounds__(256) void gemm_cost(const unsigned short* __restrict__ A,
                                                 const unsigned short* __restrict__ B,
                                                 unsigned char* __restrict__ Cq,
                                                 unsigned char* __restrict__ CTq,
                                                 unsigned* __restrict__ cmax_bits) {
  const int b = blockIdx.z;
  const int bm = blockIdx.y * 128, bn = blockIdx.x * 128;
  const int t = threadIdx.x, lane = t & 63, wv = t >> 6;
  const int wm = (wv & 1) * 64, wn = (wv >> 1) * 64;
  __shared__ unsigned short As[128 * 32];
  __shared__ unsigned short Bs[128 * 32];
  f32x4 acc[4][4];
  #pragma unroll
  for (int i = 0; i < 4; ++i)
    #pragma unroll
    for (int j = 0; j < 4; ++j) acc[i][j] = (f32x4){0.f, 0.f, 0.f, 0.f};

  const unsigned short* gA = A + (size_t)b*NPTS*NDIM + (size_t)(bm + (t >> 2))*NDIM + (t & 3)*8;
  const unsigned short* gB = B + (size_t)b*NPTS*NDIM + (size_t)(bn + (t >> 2))*NDIM + (t & 3)*8;
  const int ar = lane & 15, ak = (lane >> 4) * 8;

  for (int k0 = 0; k0 < NDIM; k0 += 32) {
    GLD_LDS16(gA + k0,             As + t*8);
    GLD_LDS16(gA + 64*NDIM + k0,   As + 2048 + t*8);
    GLD_LDS16(gB + k0,             Bs + t*8);
    GLD_LDS16(gB + 64*NDIM + k0,   Bs + 2048 + t*8);
    __syncthreads();
    short8 af[4], bq[4];
    #pragma unroll
    for (int i = 0; i < 4; ++i) af[i] = *(const short8*)(As + (wm + i*16 + ar)*32 + ak);
    #pragma unroll
    for (int j = 0; j < 4; ++j) bq[j] = *(const short8*)(Bs + (wn + j*16 + ar)*32 + ak);
    #pragma unroll
    for (int i = 0; i < 4; ++i)
      #pragma unroll
      for (int j = 0; j < 4; ++j)
        acc[i][j] = __builtin_amdgcn_mfma_f32_16x16x32_bf16(af[i], bq[j], acc[i][j], 0, 0, 0);
    __syncthreads();
  }

  float mx = 0.f;
  const int cr = (lane >> 4) * 4, cc = lane & 15;
  unsigned char* Cb = Cq  + (size_t)b * NPTS * NPTS;
  unsigned char* Tb = CTq + (size_t)b * NPTS * NPTS;
  #pragma unroll
  for (int i = 0; i < 4; ++i) {
    #pragma unroll
    for (int j = 0; j < 4; ++j) {
      const int row0 = bm + wm + i*16 + cr;
      const int col  = bn + wn + j*16 + cc;
      #pragma unroll
      for (int r = 0; r < 4; ++r) {
        float cv = 1.0f - acc[i][j][r];
        mx = fmaxf(mx, cv);
        unsigned char qv = q8(cv);
        Cb[(size_t)(row0 + r) * NPTS + col] = qv;
        Tb[(size_t)col * NPTS + row0 + r]   = qv;
      }
    }
  }
  #pragma unroll
  for (int o = 32; o; o >>= 1) mx = fmaxf(mx, __shfl_xor(mx, o, 64));
  if (lane == 0) atomicMax(cmax_bits, __float_as_uint(mx));
}

// ---------------- persistent Sinkhorn: counter barrier + matrix-in-VGPR ----------------
// 256 WGs x 512 thr. WG = (b, s) owns 64 COMPLETE outputs [s*64, s*64+64) of u and v
// (full 1024-wide dot, wave-per-row, butterfly reduce). Matrix slices for C and CT
// loaded into VGPRs ONCE: wave w, pass p handles row ob + w*8 + p; lane l holds bytes
// [16l, 16l+16) of that row (uint4). Producers store FINAL g-values, wave-contiguous.
// Sync = round-0's proven per-batch counter barrier. A sticky s_memrealtime timeout
// escapes the spin after ~1000x the expected wait: a genuine stall then completes
// with wrong output (diagnosable) instead of killing the container.

__device__ __forceinline__ float dot16(uint4 q, const float* g) {
  float a = 0.f;
  a += (float)( q.x        & 0xffu) * g[0];    // v_cvt_f32_ubyte0
  a += (float)((q.x >>  8) & 0xffu) * g[1];
  a += (float)((q.x >> 16) & 0xffu) * g[2];
  a += (float)( q.x >> 24         ) * g[3];
  a += (float)( q.y        & 0xffu) * g[4];
  a += (float)((q.y >>  8) & 0xffu) * g[5];
  a += (float)((q.y >> 16) & 0xffu) * g[6];
  a += (float)( q.y >> 24         ) * g[7];
  a += (float)( q.z        & 0xffu) * g[8];
  a += (float)((q.z >>  8) & 0xffu) * g[9];
  a += (float)((q.z >> 16) & 0xffu) * g[10];
  a += (float)( q.z >> 24         ) * g[11];
  a += (float)( q.w        & 0xffu) * g[12];
  a += (float)((q.w >>  8) & 0xffu) * g[13];
  a += (float)((q.w >> 16) & 0xffu) * g[14];
  a += (float)( q.w >> 24         ) * g[15];
  return a;
}

// lane l reads v[16l .. 16l+15] as 8 coherent 8B loads (independent, one vmcnt wait)
__device__ __forceinline__ void read_g(const float* __restrict__ src, int lane, float* gv) {
  const unsigned long long* p = (const unsigned long long*)src + lane * 8;
  #pragma unroll
  for (int k = 0; k < 8; ++k) {
    union { unsigned long long u; float f[2]; } c;
    c.u = ld_agent64(p + k);
    gv[2 * k]     = c.f[0];
    gv[2 * k + 1] = c.f[1];
  }
}

__device__ __forceinline__ void arrive(unsigned* bar) {
  __syncthreads();   // compiler emits per-wave s_waitcnt vmcnt(0) -> all stores ACKed
  if (threadIdx.x == 0)
    __hip_atomic_fetch_add(bar, 1u, __ATOMIC_RELEASE, __HIP_MEMORY_SCOPE_AGENT);
}

__device__ __forceinline__ void wait_count(unsigned* bar, unsigned target, int* s_tmo) {
  if (threadIdx.x == 0 && *s_tmo == 0) {
    const unsigned long long t0 = __builtin_amdgcn_s_memrealtime();
    while (__hip_atomic_load(bar, __ATOMIC_RELAXED, __HIP_MEMORY_SCOPE_AGENT) < target) {
      __builtin_amdgcn_s_sleep(1);
      if (__builtin_amdgcn_s_memrealtime() - t0 > SPIN_TIMEOUT_TICKS) { *s_tmo = 1; break; }
    }
    asm volatile("" ::: "memory");
  }
  __syncthreads();
}

__global__ __launch_bounds__(512) void sinkhorn_kernel(
    const unsigned char* __restrict__ Cq, const unsigned char* __restrict__ CTq,
    float* __restrict__ ubuf, float* __restrict__ vbuf,
    unsigned* __restrict__ bar, float* __restrict__ dist,
    const unsigned* __restrict__ cmax_bits)
{
  const int wg = blockIdx.x;
  const int b = wg & (NBATCH - 1);
  const int s = wg >> 4;
  const int ob = s * 64;
  const int tid = threadIdx.x, lane = tid & 63, w = tid >> 6;

  __shared__ float dred[8];
  __shared__ int s_tmo;
  if (tid == 0) s_tmo = 0;

  const float cmax  = __uint_as_float(*cmax_bits);
  const float invc2 = 1.0f / (QSCALE * cmax);   // dequant + /cmax folded

  // one-time matrix load into VGPRs: wave w, pass p -> row ob + w*8 + p
  uint4 mc[8], mt[8];
  {
    const unsigned char* cb = Cq  + (size_t)b * NPTS * NPTS;
    const unsigned char* tb = CTq + (size_t)b * NPTS * NPTS;
    #pragma unroll
    for (int p = 0; p < 8; ++p) {
      const size_t off = (size_t)(ob + w * 8 + p) * NPTS + lane * 16;
      mc[p] = *(const uint4*)(cb + off);
      mt[p] = *(const uint4*)(tb + off);
    }
  }

  float* ub = ubuf + b * NPTS;
  float* vb = vbuf + b * NPTS;
  unsigned* barb = bar + b * 64;      // 256-byte spacing per batch

  // v#0 = 1/N (true scale; producers store final values)
  if (tid < 64) st_agent(&vb[ob + tid], 1.0f / (float)NPTS);
  arrive(barb);
  unsigned bt = 16;

  float gv[16];
  float uk[8];   // final u for our 8 rows (distance epilogue)

  #pragma unroll 1
  for (int it = 0; it < 100; ++it) {
    // ---- U: u = 1/((Cq . v) * invc2 + eps)
    wait_count(barb, bt, &s_tmo);
    read_g(vb, lane, gv);
    {
      float myv = 0.f;
      #pragma unroll
      for (int p = 0; p < 8; ++p) {
        float acc = dot16(mc[p], gv);
        #pragma unroll
        for (int o = 32; o; o >>= 1) acc += __shfl_xor(acc, o, 64);
        const float val = 1.0f / (acc * invc2 + EPSI);
        uk[p] = val;
        myv = (lane == p) ? val : myv;
      }
      if (lane < 8) st_agent(&ub[ob + w * 8 + lane], myv);
    }
    arrive(barb); bt += 16;

    // ---- V: v = 1/((CTq . u) * invc2 + eps)
    wait_count(barb, bt, &s_tmo);
    read_g(ub, lane, gv);
    {
      float myv = 0.f;
      #pragma unroll
      for (int p = 0; p < 8; ++p) {
        float acc = dot16(mt[p], gv);
        #pragma unroll
        for (int o = 32; o; o >>= 1) acc += __shfl_xor(acc, o, 64);
        const float val = 1.0f / (acc * invc2 + EPSI);
        myv = (lane == p) ? val : myv;
      }
      if (lane < 8) st_agent(&vb[ob + w * 8 + lane], myv);
    }
    arrive(barb); bt += 16;
  }

  // ---- distance: d_b = sum_n u_n * (C_norm v)_n  (v#100 just published)
  wait_count(barb, bt, &s_tmo);
  read_g(vb, lane, gv);
  {
    float term = 0.f;
    #pragma unroll
    for (int p = 0; p < 8; ++p) {
      float acc = dot16(mc[p], gv);
      #pragma unroll
      for (int o = 32; o; o >>= 1) acc += __shfl_xor(acc, o, 64);
      term += uk[p] * acc;     // butterfly leaves the sum in every lane
    }
    if (lane == 0) dred[w] = term;
    __syncthreads();
    if (tid == 0) {
      float d = 0.f;
      #pragma unroll
      for (int ww = 0; ww < 8; ++ww) d += dred[ww];
      atomicAdd(dist + b, d * invc2);
    }
  }
}

__global__ void finalize_kernel(const float* __restrict__ dist, float* __restrict__ out) {
  if (threadIdx.x == 0) {
    float s = 0.f;
    for (int i = 0; i < NBATCH; ++i) s += dist[i];
    out[0] = s * (1.0f / NBATCH);
  }
}

// ---------------- launch ----------------
extern "C" void kernel_launch(void* const* d_in, const int* in_sizes, int n_in,
                              void* d_out, int out_size, void* d_ws, size_t ws_size,
                              hipStream_t stream) {
  (void)in_sizes; (void)n_in; (void)out_size; (void)ws_size;
  const float* x = (const float*)d_in[0];
  const float* y = (const float*)d_in[1];
  float* out = (float*)d_out;
  char* ws = (char*)d_ws;

  unsigned* cmax_bits = (unsigned*)ws;                 // @0
  unsigned* bar       = (unsigned*)(ws + 4096);        // 16 x 256B counters
  float*    dist      = (float*)(ws + 8192);           // 16 floats
  float*    vbuf      = (float*)(ws + 65536);          // 16 x 1024 f32 = 64 KB
  float*    ubuf      = (float*)(ws + 131072);         // 64 KB
  const size_t MB = 1u << 20;
  unsigned short* xf = (unsigned short*)(ws + 1*MB);   // 32 MB bf16
  unsigned short* yf = (unsigned short*)(ws + 33*MB);  // 32 MB bf16
  unsigned char*  C  = (unsigned char*)(ws + 65*MB);   // 16 MB u8
  unsigned char*  CT = (unsigned char*)(ws + 81*MB);   // 16 MB u8

  hipMemsetAsync(d_ws, 0, 65536, stream);  // cmax / barriers / dist

  hipLaunchKernelGGL(norm_kernel, dim3(2 * NBATCH * NPTS), dim3(256), 0, stream, x, y, xf, yf);
  hipLaunchKernelGGL(gemm_cost, dim3(8, 8, NBATCH), dim3(256), 0, stream, xf, yf, C, CT, cmax_bits);
  hipLaunchKernelGGL(sinkhorn_kernel, dim3(256), dim3(512), 0, stream, C, CT, ubuf, vbuf, bar, dist, cmax_bits);
  hipLaunchKernelGGL(finalize_kernel, dim3(1), dim3(64), 0, stream, dist, out);
}